// Round 4
// baseline (12052.312 us; speedup 1.0000x reference)
//
#include <hip/hip_runtime.h>
#include <hip/hip_fp16.h>

// TriangleMultiplicationOutgoing — MI355X (gfx950)
// ROUND 4: DUMB BISECTION BUILD. All clever machinery removed at once:
//   - no MFMA, no LDS swizzles, no global_load_lds, no bf16 weights
//   - fp32 scalar FMA throughout; weights read directly from d_in (fp32)
//   - a,b stored fp16 (rel 2^-12) transposed [c][r]; o staged fp32 in d_out
//   - g recomputed in pass3 from z (no g buffer)
//   - ws usage: 128 MB (vs 384 MB in round 3) — also tests ws-overrun theory
// If this passes: math is right, bug is in the fast machinery (or ws OOB).
// If this fails ~0.2: the shared math interpretation is wrong.

typedef unsigned short u16;
typedef unsigned int u32;
typedef unsigned short u16x8 __attribute__((ext_vector_type(8)));

#define NROW 262144  // 512*512 spatial positions
#define CH 128

__device__ __forceinline__ float sigmoidf_(float x) {
  return 1.0f / (1.0f + __expf(-x));
}

// ---------------- pass 1: LN(z) + 4 projections -> a,b (fp16, [c][r]) -------
// One row per wave; 4 rows per block; 65536 blocks.
__global__ __launch_bounds__(256) void k_pass1(
    const float* __restrict__ z, const float* __restrict__ pm,
    const float* __restrict__ lnw, const float* __restrict__ lnb,
    const float* __restrict__ wpa, const float* __restrict__ wpb,
    const float* __restrict__ wga, const float* __restrict__ wgb,
    __half* __restrict__ a_t, __half* __restrict__ b_t) {
  __shared__ float zn[4][CH];
  const int t = threadIdx.x, lane = t & 63, w = t >> 6;
  const int r = blockIdx.x * 4 + w;
  const int c0 = lane * 2;

  // LayerNorm of row r (fp32, wave shuffle reduce over 64 lanes x 2 ch)
  const float2 v = *(const float2*)(z + (size_t)r * CH + c0);
  float s = v.x + v.y, sq = v.x * v.x + v.y * v.y;
#pragma unroll
  for (int off = 32; off > 0; off >>= 1) {
    s += __shfl_xor(s, off);
    sq += __shfl_xor(sq, off);
  }
  const float mu = s * (1.0f / 128.0f);
  const float rs = rsqrtf(sq * (1.0f / 128.0f) - mu * mu + 1e-5f);
  zn[w][c0] = (v.x - mu) * rs * lnw[c0] + lnb[c0];
  zn[w][c0 + 1] = (v.y - mu) * rs * lnw[c0 + 1] + lnb[c0 + 1];
  __syncthreads();

  const float mv = pm[r];

  // Each lane computes outputs o = lane*2, lane*2+1 for all 4 matrices.
#pragma unroll
  for (int half = 0; half < 2; half++) {
    const int o = c0 + half;
    float dpa = 0.f, dga = 0.f, dpb = 0.f, dgb = 0.f;
    for (int c = 0; c < CH; c++) {
      const float zc = zn[w][c];
      dpa += wpa[o * CH + c] * zc;
      dga += wga[o * CH + c] * zc;
      dpb += wpb[o * CH + c] * zc;
      dgb += wgb[o * CH + c] * zc;
    }
    const float av = mv * sigmoidf_(dga) * dpa;
    const float bv = mv * sigmoidf_(dgb) * dpb;
    a_t[(size_t)o * NROW + r] = __float2half(av);
    b_t[(size_t)o * NROW + r] = __float2half(bv);
  }
}

// ------- pass 2: o[i,j,c] = sum_k a[i,k,c]*b[j,k,c]  (scalar fp32 tiled) ----
// Per channel c: 512x512x512 GEMM. Block = one 128x128 (i,j) tile of one c.
// Classic LDS-tiled scalar GEMM, 8x8 acc per thread. o written fp32 into
// d_out in [r][c] = [(i*512+j)*128 + c] layout (scattered; correctness run).
__global__ __launch_bounds__(256) void k_pass2(
    const __half* __restrict__ a_t, const __half* __restrict__ b_t,
    float* __restrict__ o_rc) {
  __shared__ u16 Ah[128][33];  // +1 pad breaks stride conflicts
  __shared__ u16 Bh[128][33];
  const int t = threadIdx.x;
  const int bx = blockIdx.x;
  const int c = bx >> 4, tl = bx & 15;
  const int i0 = (tl >> 2) * 128, j0 = (tl & 3) * 128;
  const u16* __restrict__ Ab = (const u16*)a_t + (size_t)c * NROW + (size_t)i0 * 512;
  const u16* __restrict__ Bb = (const u16*)b_t + (size_t)c * NROW + (size_t)j0 * 512;
  const int ig = t >> 4, jg = t & 15;  // 16x16 thread grid, 8x8 each

  float acc[8][8];
#pragma unroll
  for (int u = 0; u < 8; u++)
#pragma unroll
    for (int vv = 0; vv < 8; vv++) acc[u][vv] = 0.f;

  for (int k0 = 0; k0 < 512; k0 += 32) {
    // stage 128 rows x 32 k of A and B (vector global load, scalar LDS store)
#pragma unroll
    for (int vld = 0; vld < 2; vld++) {
      const int idx = t * 2 + vld;          // 0..511
      const int row = idx >> 2, k8 = (idx & 3) * 8;
      const u16x8 va = *(const u16x8*)(Ab + (size_t)row * 512 + k0 + k8);
      const u16x8 vb = *(const u16x8*)(Bb + (size_t)row * 512 + k0 + k8);
#pragma unroll
      for (int e = 0; e < 8; e++) {
        Ah[row][k8 + e] = va[e];
        Bh[row][k8 + e] = vb[e];
      }
    }
    __syncthreads();
    for (int k = 0; k < 32; k++) {
      float av[8], bv[8];
#pragma unroll
      for (int u = 0; u < 8; u++)
        av[u] = __half2float(*(const __half*)&Ah[ig * 8 + u][k]);
#pragma unroll
      for (int vv = 0; vv < 8; vv++)
        bv[vv] = __half2float(*(const __half*)&Bh[jg * 8 + vv][k]);
#pragma unroll
      for (int u = 0; u < 8; u++)
#pragma unroll
        for (int vv = 0; vv < 8; vv++) acc[u][vv] += av[u] * bv[vv];
    }
    __syncthreads();
  }

#pragma unroll
  for (int u = 0; u < 8; u++)
#pragma unroll
    for (int vv = 0; vv < 8; vv++) {
      const int i = i0 + ig * 8 + u, j = j0 + jg * 8 + vv;
      o_rc[(size_t)(i * 512 + j) * CH + c] = acc[u][vv];
    }
}

// ------- pass 3: out = sigmoid(zn@w_g^T) * (LN(o) @ w_o^T)  (scalar fp32) ---
// One row per wave; o read fp32 from d_out rows, overwritten in place by the
// same wave after full row consumption (no cross-wave/block overlap).
__global__ __launch_bounds__(256) void k_pass3(
    const float* __restrict__ z,
    const float* __restrict__ lnwi, const float* __restrict__ lnbi,
    const float* __restrict__ lnwo, const float* __restrict__ lnbo,
    const float* __restrict__ wg, const float* __restrict__ wo,
    float* __restrict__ out) {
  __shared__ float on[4][CH];
  __shared__ float zn[4][CH];
  const int t = threadIdx.x, lane = t & 63, w = t >> 6;
  const int r = blockIdx.x * 4 + w;
  const int c0 = lane * 2;

  // LN of o row (from d_out)
  {
    const float2 ov = *(const float2*)(out + (size_t)r * CH + c0);
    float s = ov.x + ov.y, sq = ov.x * ov.x + ov.y * ov.y;
#pragma unroll
    for (int off = 32; off > 0; off >>= 1) {
      s += __shfl_xor(s, off);
      sq += __shfl_xor(sq, off);
    }
    const float mu = s * (1.0f / 128.0f);
    const float rs = rsqrtf(sq * (1.0f / 128.0f) - mu * mu + 1e-5f);
    on[w][c0] = (ov.x - mu) * rs * lnwo[c0] + lnbo[c0];
    on[w][c0 + 1] = (ov.y - mu) * rs * lnwo[c0 + 1] + lnbo[c0 + 1];
  }
  // LN of z row (recompute zn for the gate)
  {
    const float2 zv = *(const float2*)(z + (size_t)r * CH + c0);
    float s = zv.x + zv.y, sq = zv.x * zv.x + zv.y * zv.y;
#pragma unroll
    for (int off = 32; off > 0; off >>= 1) {
      s += __shfl_xor(s, off);
      sq += __shfl_xor(sq, off);
    }
    const float mu = s * (1.0f / 128.0f);
    const float rs = rsqrtf(sq * (1.0f / 128.0f) - mu * mu + 1e-5f);
    zn[w][c0] = (zv.x - mu) * rs * lnwi[c0] + lnbi[c0];
    zn[w][c0 + 1] = (zv.y - mu) * rs * lnwi[c0 + 1] + lnbi[c0 + 1];
  }
  __syncthreads();

#pragma unroll
  for (int half = 0; half < 2; half++) {
    const int o = c0 + half;
    float dg = 0.f, dp = 0.f;
    for (int c = 0; c < CH; c++) {
      dg += wg[o * CH + c] * zn[w][c];
      dp += wo[o * CH + c] * on[w][c];
    }
    out[(size_t)r * CH + o] = sigmoidf_(dg) * dp;
  }
}

extern "C" void kernel_launch(void* const* d_in, const int* in_sizes, int n_in,
                              void* d_out, int out_size, void* d_ws, size_t ws_size,
                              hipStream_t stream) {
  const float* z = (const float*)d_in[0];
  const float* pm = (const float*)d_in[1];
  const float* ln_in_w = (const float*)d_in[2];
  const float* ln_in_b = (const float*)d_in[3];
  const float* ln_out_w = (const float*)d_in[4];
  const float* ln_out_b = (const float*)d_in[5];
  const float* w_pa = (const float*)d_in[6];
  const float* w_pb = (const float*)d_in[7];
  const float* w_ga = (const float*)d_in[8];
  const float* w_gb = (const float*)d_in[9];
  const float* w_g = (const float*)d_in[10];
  const float* w_o = (const float*)d_in[11];

  // ws: a_t | b_t (fp16, 64 MB each) = 128 MB total
  __half* a_t = (__half*)d_ws;
  __half* b_t = a_t + (size_t)CH * NROW;
  float* out = (float*)d_out;

  k_pass1<<<65536, 256, 0, stream>>>(z, pm, ln_in_w, ln_in_b,
                                     w_pa, w_pb, w_ga, w_gb, a_t, b_t);
  k_pass2<<<2048, 256, 0, stream>>>(a_t, b_t, out);
  k_pass3<<<65536, 256, 0, stream>>>(z, ln_in_w, ln_in_b, ln_out_w, ln_out_b,
                                     w_g, w_o, out);
}